// Round 1
// baseline (5033.402 us; speedup 1.0000x reference)
//
#include <hip/hip_runtime.h>
#include <hip/hip_bf16.h>
#include <math.h>

typedef __attribute__((ext_vector_type(4))) float floatx4;
typedef __attribute__((ext_vector_type(8))) __bf16 bfloatx8;
typedef __attribute__((ext_vector_type(8))) unsigned short ushortx8;

static __device__ __forceinline__ unsigned short f2bf(float f) {
  __hip_bfloat16 h = __float2bfloat16(f);
  return *reinterpret_cast<unsigned short*>(&h);
}

static __device__ __forceinline__ void gload16(const void* g, void* l) {
  __builtin_amdgcn_global_load_lds(
      (const __attribute__((address_space(1))) unsigned int*)g,
      (__attribute__((address_space(3))) unsigned int*)l, 16, 0, 0);
}

// ---------------- x: f32 -> bf16 ----------------
__global__ __launch_bounds__(256) void convert_x_kernel(const float4* __restrict__ in,
                                                        ushort4* __restrict__ out) {
  int i = blockIdx.x * 256 + threadIdx.x;
  float4 v = in[i];
  ushort4 o;
  o.x = f2bf(v.x); o.y = f2bf(v.y); o.z = f2bf(v.z); o.w = f2bf(v.w);
  out[i] = o;
}

// ------------- transpose + cast: out[c][r] = bf16(in[r][c]) -------------
__global__ __launch_bounds__(256) void transpose_bf16_kernel(const float* __restrict__ in,
                                                             unsigned short* __restrict__ out,
                                                             int rows, int cols) {
  __shared__ float tile[32][33];
  int c0 = blockIdx.x * 32, r0 = blockIdx.y * 32;
  int tx = threadIdx.x, ty = threadIdx.y;
#pragma unroll
  for (int j = 0; j < 32; j += 8)
    tile[ty + j][tx] = in[(size_t)(r0 + ty + j) * cols + c0 + tx];
  __syncthreads();
#pragma unroll
  for (int j = 0; j < 32; j += 8)
    out[(size_t)(c0 + ty + j) * rows + r0 + tx] = f2bf(tile[tx][ty + j]);
}

// ------------- lora_mid[m][r] = sum_k x[m][k] * a_down[idx][k][r] -------------
__global__ __launch_bounds__(256) void lora_mid_kernel(const float* __restrict__ x,
                                                       const float* __restrict__ a_down,
                                                       const int* __restrict__ idxp,
                                                       float* __restrict__ lmid) {
  __shared__ float ad[1024 * 9];  // padded stride 9 to avoid bank conflicts
  const float* A = a_down + (size_t)(*idxp) * (1024 * 8);
  int t = threadIdx.x;
  for (int i = t; i < 8192; i += 256) ad[(i >> 3) * 9 + (i & 7)] = A[i];
  __syncthreads();
  int wid = t >> 6, lane = t & 63;
  int row = blockIdx.x * 4 + wid;
  const float* xr = x + (size_t)row * 1024;
  float acc[8] = {0.f, 0.f, 0.f, 0.f, 0.f, 0.f, 0.f, 0.f};
  for (int i = 0; i < 16; ++i) {
    int k = i * 64 + lane;
    float xv = xr[k];
#pragma unroll
    for (int r = 0; r < 8; ++r) acc[r] += xv * ad[k * 9 + r];
  }
#pragma unroll
  for (int off = 32; off > 0; off >>= 1) {
#pragma unroll
    for (int r = 0; r < 8; ++r) acc[r] += __shfl_xor(acc[r], off);
  }
  if (lane == 0) {
    float4 v0 = make_float4(acc[0], acc[1], acc[2], acc[3]);
    float4 v1 = make_float4(acc[4], acc[5], acc[6], acc[7]);
    *(float4*)(lmid + (size_t)row * 8) = v0;
    *(float4*)(lmid + (size_t)row * 8 + 4) = v1;
  }
}

// ------------- GEMM1: H[m][f] = gelu( Xb[m][:] . W1T[f][:] + b1[f] ), bf16 out -------------
// A: Xb [16384][1024] bf16, B: W1T [4096][1024] bf16 (B^T layout), grid (32, 128)
__global__ __launch_bounds__(256) void gemm1_gelu_kernel(const unsigned short* __restrict__ A,
                                                         const unsigned short* __restrict__ B,
                                                         const float* __restrict__ bias,
                                                         unsigned short* __restrict__ H) {
  __shared__ __align__(16) char smem[16384];
  unsigned short* As = (unsigned short*)smem;           // [128][32]
  unsigned short* Bs = (unsigned short*)(smem + 8192);  // [128][32]
  const int t = threadIdx.x;
  const int wid = t >> 6, lane = t & 63;
  const int wr = wid >> 1, wc = wid & 1;
  const int lr = lane & 15, kg = lane >> 4;
  const size_t m0 = (size_t)blockIdx.y * 128;
  const size_t n0 = (size_t)blockIdx.x * 128;

  const int srow = t >> 2, scol = (t & 3) * 8;
  const unsigned short* gA0 = A + (m0 + srow) * 1024 + scol;
  const unsigned short* gA1 = A + (m0 + 64 + srow) * 1024 + scol;
  const unsigned short* gB0 = B + (n0 + srow) * 1024 + scol;
  const unsigned short* gB1 = B + (n0 + 64 + srow) * 1024 + scol;
  char* lA = smem + (wid << 10);
  char* lB = smem + 8192 + (wid << 10);

  floatx4 acc[4][4] = {};
#pragma unroll 1
  for (int kt = 0; kt < 32; ++kt) {
    const int ko = kt * 32;
    __syncthreads();
    gload16(gA0 + ko, lA);
    gload16(gA1 + ko, lA + 4096);
    gload16(gB0 + ko, lB);
    gload16(gB1 + ko, lB + 4096);
    __syncthreads();
    bfloatx8 af[4], bfv[4];
#pragma unroll
    for (int mi = 0; mi < 4; ++mi)
      af[mi] = *(const bfloatx8*)(As + (wr * 64 + mi * 16 + lr) * 32 + kg * 8);
#pragma unroll
    for (int ni = 0; ni < 4; ++ni)
      bfv[ni] = *(const bfloatx8*)(Bs + (wc * 64 + ni * 16 + lr) * 32 + kg * 8);
#pragma unroll
    for (int mi = 0; mi < 4; ++mi) {
#pragma unroll
      for (int ni = 0; ni < 4; ++ni)
        acc[mi][ni] = __builtin_amdgcn_mfma_f32_16x16x32_bf16(af[mi], bfv[ni], acc[mi][ni], 0, 0, 0);
    }
  }

  // epilogue: LDS transpose -> coalesced bf16 stores, fused bias + exact gelu
  __syncthreads();
  float* sE = (float*)smem;  // 4096 f32
  const int row32 = t >> 3, col0 = (t & 7) * 16;
  const int stripe = row32 >> 4, lrow = row32 & 15;
#pragma unroll 1
  for (int mi = 0; mi < 4; ++mi) {
#pragma unroll
    for (int ni = 0; ni < 4; ++ni) {
#pragma unroll
      for (int r = 0; r < 4; ++r)
        sE[wr * 2048 + (kg * 4 + r) * 128 + wc * 64 + ni * 16 + lr] = acc[mi][ni][r];
    }
    __syncthreads();
    const size_t gm = m0 + stripe * 64 + mi * 16 + lrow;
    const float* src = sE + stripe * 2048 + lrow * 128 + col0;
    alignas(16) unsigned short pk[16];
#pragma unroll
    for (int i = 0; i < 16; ++i) {
      float v = src[i] + bias[n0 + col0 + i];
      float g = 0.5f * v * (1.0f + erff(v * 0.70710678118654752440f));
      pk[i] = f2bf(g);
    }
    *(ushortx8*)(H + gm * 4096 + n0 + col0) = *(const ushortx8*)&pk[0];
    *(ushortx8*)(H + gm * 4096 + n0 + col0 + 8) = *(const ushortx8*)&pk[8];
    __syncthreads();
  }
}

// ------------- GEMM2: OUT[m][d] = H[m][:] . W2T[d][:] + b2[d] + lora -------------
// A: H [16384][4096] bf16, B: W2T [1024][4096] bf16, grid (8, 128)
__global__ __launch_bounds__(256) void gemm2_out_kernel(const unsigned short* __restrict__ A,
                                                        const unsigned short* __restrict__ B,
                                                        const float* __restrict__ bias,
                                                        const float* __restrict__ lmid,
                                                        const float* __restrict__ a_up,
                                                        const int* __restrict__ idxp,
                                                        float* __restrict__ OUT) {
  __shared__ __align__(16) char smem[16384];
  unsigned short* As = (unsigned short*)smem;
  unsigned short* Bs = (unsigned short*)(smem + 8192);
  const int t = threadIdx.x;
  const int wid = t >> 6, lane = t & 63;
  const int wr = wid >> 1, wc = wid & 1;
  const int lr = lane & 15, kg = lane >> 4;
  const size_t m0 = (size_t)blockIdx.y * 128;
  const size_t n0 = (size_t)blockIdx.x * 128;

  const int srow = t >> 2, scol = (t & 3) * 8;
  const unsigned short* gA0 = A + (m0 + srow) * 4096 + scol;
  const unsigned short* gA1 = A + (m0 + 64 + srow) * 4096 + scol;
  const unsigned short* gB0 = B + (n0 + srow) * 4096 + scol;
  const unsigned short* gB1 = B + (n0 + 64 + srow) * 4096 + scol;
  char* lA = smem + (wid << 10);
  char* lB = smem + 8192 + (wid << 10);

  floatx4 acc[4][4] = {};
#pragma unroll 1
  for (int kt = 0; kt < 128; ++kt) {
    const int ko = kt * 32;
    __syncthreads();
    gload16(gA0 + ko, lA);
    gload16(gA1 + ko, lA + 4096);
    gload16(gB0 + ko, lB);
    gload16(gB1 + ko, lB + 4096);
    __syncthreads();
    bfloatx8 af[4], bfv[4];
#pragma unroll
    for (int mi = 0; mi < 4; ++mi)
      af[mi] = *(const bfloatx8*)(As + (wr * 64 + mi * 16 + lr) * 32 + kg * 8);
#pragma unroll
    for (int ni = 0; ni < 4; ++ni)
      bfv[ni] = *(const bfloatx8*)(Bs + (wc * 64 + ni * 16 + lr) * 32 + kg * 8);
#pragma unroll
    for (int mi = 0; mi < 4; ++mi) {
#pragma unroll
      for (int ni = 0; ni < 4; ++ni)
        acc[mi][ni] = __builtin_amdgcn_mfma_f32_16x16x32_bf16(af[mi], bfv[ni], acc[mi][ni], 0, 0, 0);
    }
  }

  // epilogue: LDS transpose -> coalesced f32 stores, fused bias + LoRA residual
  __syncthreads();
  float* sE = (float*)smem;
  const float* aup = a_up + (size_t)(*idxp) * 8192;
  const int row32 = t >> 3, col0 = (t & 7) * 16;
  const int stripe = row32 >> 4, lrow = row32 & 15;
#pragma unroll 1
  for (int mi = 0; mi < 4; ++mi) {
#pragma unroll
    for (int ni = 0; ni < 4; ++ni) {
#pragma unroll
      for (int r = 0; r < 4; ++r)
        sE[wr * 2048 + (kg * 4 + r) * 128 + wc * 64 + ni * 16 + lr] = acc[mi][ni][r];
    }
    __syncthreads();
    const size_t gm = m0 + stripe * 64 + mi * 16 + lrow;
    const float* src = sE + stripe * 2048 + lrow * 128 + col0;
    alignas(16) float lmv[8];
    *(float4*)&lmv[0] = *(const float4*)(lmid + gm * 8);
    *(float4*)&lmv[4] = *(const float4*)(lmid + gm * 8 + 4);
    alignas(16) float v[16];
#pragma unroll
    for (int i = 0; i < 16; ++i) v[i] = src[i] + bias[n0 + col0 + i];
#pragma unroll
    for (int r = 0; r < 8; ++r) {
      const float lw = lmv[r];
      const float* ar = aup + r * 1024 + n0 + col0;
#pragma unroll
      for (int i = 0; i < 16; ++i) v[i] += lw * ar[i];
    }
#pragma unroll
    for (int i = 0; i < 16; i += 4)
      *(float4*)(OUT + gm * 1024 + n0 + col0 + i) = *(const float4*)&v[i];
    __syncthreads();
  }
}

extern "C" void kernel_launch(void* const* d_in, const int* in_sizes, int n_in,
                              void* d_out, int out_size, void* d_ws, size_t ws_size,
                              hipStream_t stream) {
  const float* x      = (const float*)d_in[0];
  const float* w1     = (const float*)d_in[1];
  const float* b1     = (const float*)d_in[2];
  const float* w2     = (const float*)d_in[3];
  const float* b2     = (const float*)d_in[4];
  const float* a_down = (const float*)d_in[5];
  const float* a_up   = (const float*)d_in[6];
  const int*   idx    = (const int*)d_in[7];
  float* out = (float*)d_out;

  char* ws = (char*)d_ws;
  unsigned short* Xb  = (unsigned short*)(ws);              // 16384x1024 bf16 = 32 MiB
  unsigned short* W1T = (unsigned short*)(ws + 33554432);   // 4096x1024 bf16 = 8 MiB
  unsigned short* W2T = (unsigned short*)(ws + 41943040);   // 1024x4096 bf16 = 8 MiB
  float*          LMID = (float*)(ws + 50331648);           // 16384x8 f32 = 0.5 MiB
  unsigned short* H   = (unsigned short*)(ws + 50855936);   // 16384x4096 bf16 = 128 MiB

  convert_x_kernel<<<16384, 256, 0, stream>>>((const float4*)x, (ushort4*)Xb);
  transpose_bf16_kernel<<<dim3(128, 32), dim3(32, 8), 0, stream>>>(w1, W1T, 1024, 4096);
  transpose_bf16_kernel<<<dim3(32, 128), dim3(32, 8), 0, stream>>>(w2, W2T, 4096, 1024);
  lora_mid_kernel<<<4096, 256, 0, stream>>>(x, a_down, idx, LMID);
  gemm1_gelu_kernel<<<dim3(32, 128), 256, 0, stream>>>(Xb, W1T, b1, H);
  gemm2_out_kernel<<<dim3(8, 128), 256, 0, stream>>>(H, W2T, b2, LMID, a_up, idx, out);
}

// Round 2
// 700.741 us; speedup vs baseline: 7.1830x; 7.1830x over previous
//
#include <hip/hip_runtime.h>
#include <hip/hip_bf16.h>
#include <math.h>

typedef __attribute__((ext_vector_type(4))) float floatx4;
typedef __attribute__((ext_vector_type(8))) __bf16 bfloatx8;
typedef __attribute__((ext_vector_type(8))) unsigned short ushortx8;

static __device__ __forceinline__ unsigned short f2bf(float f) {
  __hip_bfloat16 h = __float2bfloat16(f);
  return *reinterpret_cast<unsigned short*>(&h);
}

static __device__ __forceinline__ void gload16(const void* g, void* l) {
  __builtin_amdgcn_global_load_lds(
      (const __attribute__((address_space(1))) unsigned int*)g,
      (__attribute__((address_space(3))) unsigned int*)l, 16, 0, 0);
}

// ---------------- x: f32 -> bf16 ----------------
__global__ __launch_bounds__(256) void convert_x_kernel(const float4* __restrict__ in,
                                                        ushort4* __restrict__ out) {
  int i = blockIdx.x * 256 + threadIdx.x;
  float4 v = in[i];
  ushort4 o;
  o.x = f2bf(v.x); o.y = f2bf(v.y); o.z = f2bf(v.z); o.w = f2bf(v.w);
  out[i] = o;
}

// ------------- transpose + cast: out[c][r] = bf16(in[r][c]) -------------
__global__ __launch_bounds__(256) void transpose_bf16_kernel(const float* __restrict__ in,
                                                             unsigned short* __restrict__ out,
                                                             int rows, int cols) {
  __shared__ float tile[32][33];
  int c0 = blockIdx.x * 32, r0 = blockIdx.y * 32;
  int tx = threadIdx.x, ty = threadIdx.y;
#pragma unroll
  for (int j = 0; j < 32; j += 8)
    tile[ty + j][tx] = in[(size_t)(r0 + ty + j) * cols + c0 + tx];
  __syncthreads();
#pragma unroll
  for (int j = 0; j < 32; j += 8)
    out[(size_t)(c0 + ty + j) * rows + r0 + tx] = f2bf(tile[tx][ty + j]);
}

// ------------- lora_mid[m][r] = sum_k x[m][k] * a_down[idx][k][r] -------------
__global__ __launch_bounds__(256) void lora_mid_kernel(const float* __restrict__ x,
                                                       const float* __restrict__ a_down,
                                                       const int* __restrict__ idxp,
                                                       float* __restrict__ lmid) {
  __shared__ float ad[1024 * 9];  // padded stride 9 to avoid bank conflicts
  const float* A = a_down + (size_t)(*idxp) * (1024 * 8);
  int t = threadIdx.x;
  for (int i = t; i < 8192; i += 256) ad[(i >> 3) * 9 + (i & 7)] = A[i];
  __syncthreads();
  int wid = t >> 6, lane = t & 63;
  int row = blockIdx.x * 4 + wid;
  const float* xr = x + (size_t)row * 1024;
  float acc[8] = {0.f, 0.f, 0.f, 0.f, 0.f, 0.f, 0.f, 0.f};
  for (int i = 0; i < 16; ++i) {
    int k = i * 64 + lane;
    float xv = xr[k];
#pragma unroll
    for (int r = 0; r < 8; ++r) acc[r] += xv * ad[k * 9 + r];
  }
#pragma unroll
  for (int off = 32; off > 0; off >>= 1) {
#pragma unroll
    for (int r = 0; r < 8; ++r) acc[r] += __shfl_xor(acc[r], off);
  }
  if (lane == 0) {
    float4 v0 = make_float4(acc[0], acc[1], acc[2], acc[3]);
    float4 v1 = make_float4(acc[4], acc[5], acc[6], acc[7]);
    *(float4*)(lmid + (size_t)row * 8) = v0;
    *(float4*)(lmid + (size_t)row * 8 + 4) = v1;
  }
}

// ------------- GEMM1: H[m][f] = gelu( Xb[m][:] . W1T[f][:] + b1[f] ), bf16 out -------------
// A: Xb [16384][1024] bf16, B: W1T [4096][1024] bf16 (B^T layout), grid (32, 128)
__global__ __launch_bounds__(256) void gemm1_gelu_kernel(const unsigned short* __restrict__ A,
                                                         const unsigned short* __restrict__ B,
                                                         const float* __restrict__ bias,
                                                         unsigned short* __restrict__ H) {
  __shared__ __align__(16) char smem[16384];
  unsigned short* As = (unsigned short*)smem;           // [128][32]
  unsigned short* Bs = (unsigned short*)(smem + 8192);  // [128][32]
  const int t = threadIdx.x;
  const int wid = t >> 6, lane = t & 63;
  const int wr = wid >> 1, wc = wid & 1;
  const int lr = lane & 15, kg = lane >> 4;
  const size_t m0 = (size_t)blockIdx.y * 128;
  const size_t n0 = (size_t)blockIdx.x * 128;

  const int srow = t >> 2, scol = (t & 3) * 8;
  const unsigned short* gA0 = A + (m0 + srow) * 1024 + scol;
  const unsigned short* gA1 = A + (m0 + 64 + srow) * 1024 + scol;
  const unsigned short* gB0 = B + (n0 + srow) * 1024 + scol;
  const unsigned short* gB1 = B + (n0 + 64 + srow) * 1024 + scol;
  char* lA = smem + (wid << 10);
  char* lB = smem + 8192 + (wid << 10);

  floatx4 acc[4][4] = {};
#pragma unroll 1
  for (int kt = 0; kt < 32; ++kt) {
    const int ko = kt * 32;
    __syncthreads();
    gload16(gA0 + ko, lA);
    gload16(gA1 + ko, lA + 4096);
    gload16(gB0 + ko, lB);
    gload16(gB1 + ko, lB + 4096);
    __syncthreads();
    bfloatx8 af[4], bfv[4];
#pragma unroll
    for (int mi = 0; mi < 4; ++mi)
      af[mi] = *(const bfloatx8*)(As + (wr * 64 + mi * 16 + lr) * 32 + kg * 8);
#pragma unroll
    for (int ni = 0; ni < 4; ++ni)
      bfv[ni] = *(const bfloatx8*)(Bs + (wc * 64 + ni * 16 + lr) * 32 + kg * 8);
#pragma unroll
    for (int mi = 0; mi < 4; ++mi) {
#pragma unroll
      for (int ni = 0; ni < 4; ++ni)
        acc[mi][ni] = __builtin_amdgcn_mfma_f32_16x16x32_bf16(af[mi], bfv[ni], acc[mi][ni], 0, 0, 0);
    }
  }

  // epilogue: LDS transpose -> coalesced bf16 stores, fused bias + exact gelu
  // FULLY UNROLLED mi loop: acc[] must stay compile-time indexed (rule #20 —
  // runtime index demotes the accumulator array to scratch; cost was 8.7 GB
  // of scratch traffic and MfmaUtil 2%).
  __syncthreads();
  float* sE = (float*)smem;  // 4096 f32
  const int row32 = t >> 3, col0 = (t & 7) * 16;
  const int stripe = row32 >> 4, lrow = row32 & 15;
#pragma unroll
  for (int mi = 0; mi < 4; ++mi) {
#pragma unroll
    for (int ni = 0; ni < 4; ++ni) {
#pragma unroll
      for (int r = 0; r < 4; ++r)
        sE[wr * 2048 + (kg * 4 + r) * 128 + wc * 64 + ni * 16 + lr] = acc[mi][ni][r];
    }
    __syncthreads();
    const size_t gm = m0 + stripe * 64 + mi * 16 + lrow;
    const float* src = sE + stripe * 2048 + lrow * 128 + col0;
    alignas(16) unsigned short pk[16];
#pragma unroll
    for (int i = 0; i < 16; ++i) {
      float v = src[i] + bias[n0 + col0 + i];
      float g = 0.5f * v * (1.0f + erff(v * 0.70710678118654752440f));
      pk[i] = f2bf(g);
    }
    *(ushortx8*)(H + gm * 4096 + n0 + col0) = *(const ushortx8*)&pk[0];
    *(ushortx8*)(H + gm * 4096 + n0 + col0 + 8) = *(const ushortx8*)&pk[8];
    __syncthreads();
  }
}

// ------------- GEMM2: OUT[m][d] = H[m][:] . W2T[d][:] + b2[d] + lora -------------
// A: H [16384][4096] bf16, B: W2T [1024][4096] bf16, grid (8, 128)
__global__ __launch_bounds__(256) void gemm2_out_kernel(const unsigned short* __restrict__ A,
                                                        const unsigned short* __restrict__ B,
                                                        const float* __restrict__ bias,
                                                        const float* __restrict__ lmid,
                                                        const float* __restrict__ a_up,
                                                        const int* __restrict__ idxp,
                                                        float* __restrict__ OUT) {
  __shared__ __align__(16) char smem[16384];
  unsigned short* As = (unsigned short*)smem;
  unsigned short* Bs = (unsigned short*)(smem + 8192);
  const int t = threadIdx.x;
  const int wid = t >> 6, lane = t & 63;
  const int wr = wid >> 1, wc = wid & 1;
  const int lr = lane & 15, kg = lane >> 4;
  const size_t m0 = (size_t)blockIdx.y * 128;
  const size_t n0 = (size_t)blockIdx.x * 128;

  const int srow = t >> 2, scol = (t & 3) * 8;
  const unsigned short* gA0 = A + (m0 + srow) * 4096 + scol;
  const unsigned short* gA1 = A + (m0 + 64 + srow) * 4096 + scol;
  const unsigned short* gB0 = B + (n0 + srow) * 4096 + scol;
  const unsigned short* gB1 = B + (n0 + 64 + srow) * 4096 + scol;
  char* lA = smem + (wid << 10);
  char* lB = smem + 8192 + (wid << 10);

  floatx4 acc[4][4] = {};
#pragma unroll 1
  for (int kt = 0; kt < 128; ++kt) {
    const int ko = kt * 32;
    __syncthreads();
    gload16(gA0 + ko, lA);
    gload16(gA1 + ko, lA + 4096);
    gload16(gB0 + ko, lB);
    gload16(gB1 + ko, lB + 4096);
    __syncthreads();
    bfloatx8 af[4], bfv[4];
#pragma unroll
    for (int mi = 0; mi < 4; ++mi)
      af[mi] = *(const bfloatx8*)(As + (wr * 64 + mi * 16 + lr) * 32 + kg * 8);
#pragma unroll
    for (int ni = 0; ni < 4; ++ni)
      bfv[ni] = *(const bfloatx8*)(Bs + (wc * 64 + ni * 16 + lr) * 32 + kg * 8);
#pragma unroll
    for (int mi = 0; mi < 4; ++mi) {
#pragma unroll
      for (int ni = 0; ni < 4; ++ni)
        acc[mi][ni] = __builtin_amdgcn_mfma_f32_16x16x32_bf16(af[mi], bfv[ni], acc[mi][ni], 0, 0, 0);
    }
  }

  // epilogue: LDS transpose -> coalesced f32 stores, fused bias + LoRA residual
  // FULLY UNROLLED mi loop (rule #20, see gemm1).
  __syncthreads();
  float* sE = (float*)smem;
  const float* aup = a_up + (size_t)(*idxp) * 8192;
  const int row32 = t >> 3, col0 = (t & 7) * 16;
  const int stripe = row32 >> 4, lrow = row32 & 15;
#pragma unroll
  for (int mi = 0; mi < 4; ++mi) {
#pragma unroll
    for (int ni = 0; ni < 4; ++ni) {
#pragma unroll
      for (int r = 0; r < 4; ++r)
        sE[wr * 2048 + (kg * 4 + r) * 128 + wc * 64 + ni * 16 + lr] = acc[mi][ni][r];
    }
    __syncthreads();
    const size_t gm = m0 + stripe * 64 + mi * 16 + lrow;
    const float* src = sE + stripe * 2048 + lrow * 128 + col0;
    alignas(16) float lmv[8];
    *(float4*)&lmv[0] = *(const float4*)(lmid + gm * 8);
    *(float4*)&lmv[4] = *(const float4*)(lmid + gm * 8 + 4);
    alignas(16) float v[16];
#pragma unroll
    for (int i = 0; i < 16; ++i) v[i] = src[i] + bias[n0 + col0 + i];
#pragma unroll
    for (int r = 0; r < 8; ++r) {
      const float lw = lmv[r];
      const float* ar = aup + r * 1024 + n0 + col0;
#pragma unroll
      for (int i = 0; i < 16; ++i) v[i] += lw * ar[i];
    }
#pragma unroll
    for (int i = 0; i < 16; i += 4)
      *(float4*)(OUT + gm * 1024 + n0 + col0 + i) = *(const float4*)&v[i];
    __syncthreads();
  }
}

extern "C" void kernel_launch(void* const* d_in, const int* in_sizes, int n_in,
                              void* d_out, int out_size, void* d_ws, size_t ws_size,
                              hipStream_t stream) {
  const float* x      = (const float*)d_in[0];
  const float* w1     = (const float*)d_in[1];
  const float* b1     = (const float*)d_in[2];
  const float* w2     = (const float*)d_in[3];
  const float* b2     = (const float*)d_in[4];
  const float* a_down = (const float*)d_in[5];
  const float* a_up   = (const float*)d_in[6];
  const int*   idx    = (const int*)d_in[7];
  float* out = (float*)d_out;

  char* ws = (char*)d_ws;
  unsigned short* Xb  = (unsigned short*)(ws);              // 16384x1024 bf16 = 32 MiB
  unsigned short* W1T = (unsigned short*)(ws + 33554432);   // 4096x1024 bf16 = 8 MiB
  unsigned short* W2T = (unsigned short*)(ws + 41943040);   // 1024x4096 bf16 = 8 MiB
  float*          LMID = (float*)(ws + 50331648);           // 16384x8 f32 = 0.5 MiB
  unsigned short* H   = (unsigned short*)(ws + 50855936);   // 16384x4096 bf16 = 128 MiB

  convert_x_kernel<<<16384, 256, 0, stream>>>((const float4*)x, (ushort4*)Xb);
  transpose_bf16_kernel<<<dim3(128, 32), dim3(32, 8), 0, stream>>>(w1, W1T, 1024, 4096);
  transpose_bf16_kernel<<<dim3(32, 128), dim3(32, 8), 0, stream>>>(w2, W2T, 4096, 1024);
  lora_mid_kernel<<<4096, 256, 0, stream>>>(x, a_down, idx, LMID);
  gemm1_gelu_kernel<<<dim3(32, 128), 256, 0, stream>>>(Xb, W1T, b1, H);
  gemm2_out_kernel<<<dim3(8, 128), 256, 0, stream>>>(H, W2T, b2, LMID, a_up, idx, out);
}